// Round 6
// baseline (162.803 us; speedup 1.0000x reference)
//
#include <hip/hip_runtime.h>

// out[b, c, w, f] = X[b, c, f*HOP + w]
// B=16, C=2, T=262144, WINDOW=1024, HOP=256, NF=1021
#define WINDOW_SZ 1024
#define HOP_SZ    256
#define NFRAMES   1021
#define T_LEN     262144
#define NLINES_TOT 1024   // input frames (64B lines per (bc,wg) column)

#define CHUNK  256        // frames per block
#define SLINES 260        // staged lines: CHUNK + 3 (k-shift) + 1
#define LSTR   260        // lds row stride in floats

typedef float f4  __attribute__((ext_vector_type(4)));
typedef float f4u __attribute__((ext_vector_type(4), aligned(4)));

// Read-once / write-once, chunked for occupancy:
//  - block (bc, wg, fc) reads bytes [wg*64, wg*64+64) of frames
//    [fc*256, fc*256+260): 64B full-line reads, 1KiB stride; only the 4-line
//    chunk overlap (k-shift) is re-read (+1.2%).
//  - it writes rows w = 256k + 16wg + r (k=0..3, r=0..15), f-segment
//    [fc*256, fc*256+256): byte offset fc*1024 within 64B-aligned rows ->
//    every store segment is full 64B lines, no RMW.
//  - LDS 16.25 KiB, 256 threads -> 8 blocks/CU, 32 waves/CU (100% occupancy)
//    vs round-5's 2 blocks / 16 waves: the latency-hiding fix.
__global__ __launch_bounds__(256, 8)
void frame_transpose_kernel(const float* __restrict__ X,
                            float* __restrict__ out) {
    __shared__ float lds[16 * LSTR];   // lds[r][line], 16.25 KiB

    const int bid = blockIdx.x;        // 2048 blocks
    const int fc  = bid & 3;           // frame chunk 0..3
    const int wg  = (bid >> 2) & 15;   // 64B sub-line 0..15
    const int bc  = bid >> 6;          // slab 0..31
    const int t   = threadIdx.x;

    const int L0 = fc * CHUNK;
    const float* Xb = X + (size_t)bc * T_LEN + wg * 16;

    // ---- phase 1: stage 260 lines (read-once + 4-line shift overlap) ----
    // 260 lines x 4 quads = 1040 tasks; wave instr = 16 full 64B lines.
#pragma unroll
    for (int p = 0; p < 5; ++p) {
        const int idx = p * 256 + t;
        if (idx < 4 * SLINES) {
            const int line = idx >> 2;
            const int sub  = idx & 3;
            if (L0 + line < NLINES_TOT) {
                const f4 v = *(const f4*)(Xb + (size_t)(L0 + line) * HOP_SZ + 4 * sub);
                const int r0 = 4 * sub;
                // bank = (16*(l&3) + (l>>2) + 4j + c) % 32 -> 2-way only (free)
                lds[(r0 + 0) * LSTR + line] = v.x;
                lds[(r0 + 1) * LSTR + line] = v.y;
                lds[(r0 + 2) * LSTR + line] = v.z;
                lds[(r0 + 3) * LSTR + line] = v.w;
            }
        }
    }

    __syncthreads();

    // ---- phase 2: 4 k-regions x 16 rows x 64 f4-slots, all full-line ----
    // slot = p*256 + t: k = p>>2 and row = (p&3)*4 + wave-id are
    // compile-time/wave-uniform under unroll; pos = lane-consecutive ->
    // each wave store = 1024B contiguous.
    float* outb = out + ((size_t)(bc * WINDOW_SZ + 16 * wg)) * NFRAMES + fc * CHUNK;
#pragma unroll
    for (int p = 0; p < 16; ++p) {
        const int slot = p * 256 + t;
        const int k    = slot >> 10;       // 0..3 (constant per unrolled p)
        const int rem  = slot & 1023;
        const int row  = rem >> 6;         // 0..15 (wave-uniform)
        const int pos  = rem & 63;         // f4 slot in segment
        const int fbase = L0 + 4 * pos;
        const float* lrow = &lds[row * LSTR + 4 * pos];
        float* oaddr = outb + (size_t)(256 * k + row) * NFRAMES + 4 * pos;
        if (fbase + 3 <= NFRAMES - 1) {
            // aligned b128 pair + compile-time-k register shuffle
            const f4 q0 = *(const f4*)(lrow);
            const f4 q1 = *(const f4*)(lrow + 4);
            f4 o;
            if      (k == 0) o = q0;
            else if (k == 1) o = f4{q0.y, q0.z, q0.w, q1.x};
            else if (k == 2) o = f4{q0.z, q0.w, q1.x, q1.y};
            else             o = f4{q0.w, q1.x, q1.y, q1.z};
            *(f4u*)oaddr = o;              // rows 1021-strided: 4B-aligned vec4
        } else if (fbase <= NFRAMES - 1) {
            // fc=3, pos=63: only f=1020 valid
            *oaddr = lrow[k];
        }
    }
}

extern "C" void kernel_launch(void* const* d_in, const int* in_sizes, int n_in,
                              void* d_out, int out_size, void* d_ws, size_t ws_size,
                              hipStream_t stream) {
    const float* X = (const float*)d_in[0];
    float* out = (float*)d_out;

    dim3 block(256, 1, 1);
    dim3 grid(32 * 16 * 4, 1, 1);   // bc x wg x fc = 2048 blocks, 8 per CU
    frame_transpose_kernel<<<grid, block, 0, stream>>>(X, out);
}

// Round 7
// 157.446 us; speedup vs baseline: 1.0340x; 1.0340x over previous
//
#include <hip/hip_runtime.h>

// out[b, c, w, f] = X[b, c, f*HOP + w]
// B=16, C=2, T=262144, WINDOW=1024, HOP=256, NF=1021
#define WINDOW_SZ 1024
#define HOP_SZ    256
#define NFRAMES   1021
#define T_LEN     262144

#define NLINES 1024   // frames staged per block (1021 used + 3 for the k-shift)
#define LSTR   1028   // LDS row stride: 1028 % 32 == 4 -> phase-1 writes 2-way (free), was 4-way at 1024
#define WG_ROWS 16    // w-offsets per block = one 64B sub-line of every frame

typedef float f4  __attribute__((ext_vector_type(4)));
typedef float f4u __attribute__((ext_vector_type(4), aligned(4)));

// Round-5 structure (best measured: 157.4) + LDS bank fix. A/B repeat to
// separate signal from harness noise.
//  - block (bc, wg) reads bytes [wg*64, wg*64+64) of every 1KB frame in slab bc:
//    1024 full aligned 64B lines, each input byte read EXACTLY ONCE globally.
//  - it owns output rows w = 256k + 16wg + r (k=0..3, r=0..15): 4 contiguous
//    regions of 16*1021 floats = 65,344 B = exactly 1021 full aligned 64B
//    lines each -> no partial-line RMW anywhere.
//  - out[w][f] = X[256(f+k) + 16wg + r] = lds[r][f+k]: k-shift = two aligned
//    b128 LDS reads + compile-time register shuffle.
__global__ __launch_bounds__(512)
void frame_transpose_kernel(const float* __restrict__ X,
                            float* __restrict__ out) {
    __shared__ float lds[WG_ROWS * LSTR];   // 64.25 KiB -> 2 blocks/CU, 512 blocks = 2/CU exactly

    const int bid = blockIdx.x;
    const int bc  = bid >> 4;     // 0..31
    const int wg  = bid & 15;     // 0..15
    const int t   = threadIdx.x;

    const float* Xbc = X + (size_t)bc * T_LEN + wg * 16;

    // ---- phase 1: 8 x f4 loads/thread, every line fetched once ----
    // wave instr = 16 distinct full 64B lines (4 lanes per line), coalesced.
#pragma unroll
    for (int p = 0; p < 8; ++p) {
        const int idx  = p * 512 + t;     // 0..4095
        const int line = idx >> 2;        // frame 0..1023
        const int sub  = idx & 3;         // f4 within the 64B line
        const f4 v = *(const f4*)(Xbc + line * HOP_SZ + 4 * sub);
        // lds[r][line], r = 4*sub..4*sub+3; stride 1028 -> bank (16(l&3)+line)%32,
        // 2-way only (free)
        lds[(4 * sub + 0) * LSTR + line] = v.x;
        lds[(4 * sub + 1) * LSTR + line] = v.y;
        lds[(4 * sub + 2) * LSTR + line] = v.z;
        lds[(4 * sub + 3) * LSTR + line] = v.w;
    }

    __syncthreads();

    // ---- phase 2: 4 output regions, all full-line writes ----
#pragma unroll
    for (int k = 0; k < 4; ++k) {
        float* obase = out + (size_t)(bc * WINDOW_SZ + 256 * k + 16 * wg) * NFRAMES;
#pragma unroll
        for (int p = 0; p < 8; ++p) {
            const int slot = p * 512 + t;   // 0..4095 = 16 rows x 256 slots
            const int row  = slot >> 8;     // r = 0..15 (wave-uniform)
            const int pos  = slot & 255;    // f4 slot in the row
            const float* lrow = &lds[row * LSTR + 4 * pos];   // 16B-aligned (1028*4 % 16 == 0)
            if (pos < 255) {
                // aligned b128 pair (consecutive lanes -> consecutive quads, conflict-free)
                const f4 q0 = *(const f4*)(lrow);
                const f4 q1 = *(const f4*)(lrow + 4);
                f4 o;
                if      (k == 0) o = q0;
                else if (k == 1) o = f4{q0.y, q0.z, q0.w, q1.x};
                else if (k == 2) o = f4{q0.z, q0.w, q1.x, q1.y};
                else             o = f4{q0.w, q1.x, q1.y, q1.z};
                // rows are 1021-strided -> only 4B-aligned: unaligned-capable vec4 store
                *(f4u*)(obase + (size_t)row * NFRAMES + 4 * pos) = o;
            } else {
                // row tail: f = 1020 (1021 = 255*4 + 1)
                obase[(size_t)row * NFRAMES + 1020] = lrow[k];
            }
        }
    }
}

extern "C" void kernel_launch(void* const* d_in, const int* in_sizes, int n_in,
                              void* d_out, int out_size, void* d_ws, size_t ws_size,
                              hipStream_t stream) {
    const float* X = (const float*)d_in[0];
    float* out = (float*)d_out;

    dim3 block(512, 1, 1);
    dim3 grid(32 * 16, 1, 1);   // bc (32) x wg (16): 512 blocks, 2 per CU
    frame_transpose_kernel<<<grid, block, 0, stream>>>(X, out);
}